// Round 9
// baseline (610.240 us; speedup 1.0000x reference)
//
#include <hip/hip_runtime.h>
#include <stdint.h>

typedef unsigned short u16;
typedef unsigned int   u32;

#define N_NODES  100000
#define N_EDGES  1600000
#define DFEAT    128
#define N_GRAPHS 512

#define NBKT   391    // buckets of 256 nodes (ceil(N/256))
#define EPB    8192   // edges per block in hist/scatter
#define NBLK_E 196    // ceil(N_EDGES/EPB)
#define LBUF   8192   // per-bucket capacity (mean 4096, sigma ~64)

// Sliced activation layout: HS[slice][node][16 bf16], slice = 0..7.
// One slice = 100000*32B = 3.2MB -> fits a 4MiB per-XCD L2. agg blocks pin
// slice = blockIdx&7 (XCD round-robin), so gathers hit L2 after warmup.
#define SL_STRIDE ((size_t)N_NODES * 16)   // u16s per slice

typedef float f32x4 __attribute__((ext_vector_type(4)));
typedef short s16x8 __attribute__((ext_vector_type(8)));
typedef unsigned int u32x4 __attribute__((ext_vector_type(4)));

__device__ __forceinline__ float bflo(u32 u) { return __uint_as_float(u << 16); }
__device__ __forceinline__ float bfhi(u32 u) { return __uint_as_float(u & 0xffff0000u); }
__device__ __forceinline__ u16 f2bf(float f) {
  u32 u = __float_as_uint(f);
  return (u16)((u + 0x7fffu + ((u >> 16) & 1u)) >> 16);   // RNE
}
__device__ __forceinline__ u32 pack2(float f0, float f1) {
  return (u32)f2bf(f0) | ((u32)f2bf(f1) << 16);
}
__device__ __forceinline__ void nt_store16(void* p, uint4 v) {
  u32x4 w; w.x = v.x; w.y = v.y; w.z = v.z; w.w = v.w;
  __builtin_nontemporal_store(w, (u32x4*)p);
}

__device__ __forceinline__ int ld_src(const int* ei, int m, int e) {
  return m ? ei[2 * e] : ei[e];
}
__device__ __forceinline__ int ld_dst(const int* ei, int m, int e) {
  return m ? ei[2 * (N_EDGES + e)] : ei[N_EDGES + e];
}

// block-local int64-vs-int32 detect (odd words of first 64 edge slots all zero <=> int64)
__device__ __forceinline__ int detect_m_block(const int* __restrict__ ei, int* sm) {
  int t = threadIdx.x;
  if (t < 64) {
    int v = ei[2 * t + 1];
    unsigned long long b = __ballot(v != 0);
    if (t == 0) *sm = (b == 0ull) ? 1 : 0;
  }
  __syncthreads();
  return *sm;
}

__device__ __forceinline__ int lower_bound_i(const int* a, int n, int key, int shift) {
  int lo = 0, hi = n;
  while (lo < hi) {
    int mid = (lo + hi) >> 1;
    if (a[mid << shift] < key) lo = mid + 1; else hi = mid;
  }
  return lo;
}

// ---------------- pass A: per-block bucket histogram + W cvt + flag ----------------
__global__ __launch_bounds__(256) void histA_k(const int* __restrict__ ei,
                                               int* __restrict__ ghist,
                                               const float* __restrict__ W1,
                                               const float* __restrict__ W2,
                                               const float* __restrict__ W3,
                                               u16* __restrict__ T1, u16* __restrict__ T2,
                                               u16* __restrict__ T3, int* __restrict__ flag) {
  int t = threadIdx.x, b = blockIdx.x;
  if (b >= NBLK_E) {
    int r = b - NBLK_E;
    if (r < 3) {   // W transpose+convert
      const float* W = (r == 0) ? W1 : (r == 1) ? W2 : W3;
      u16* T         = (r == 0) ? T1 : (r == 1) ? T2 : T3;
      for (int i = t; i < DFEAT * DFEAT; i += 256) {
        int n = i >> 7, k = i & 127;
        T[i] = f2bf(W[k * DFEAT + n]);
      }
    } else {       // flag for pool_k
      if (t < 64) {
        int v = ei[2 * t + 1];
        unsigned long long mm = __ballot(v != 0);
        if (t == 0) *flag = (mm == 0ull) ? 1 : 0;
      }
    }
    return;
  }
  __shared__ int sm;
  __shared__ int hist[NBKT];
  int m = detect_m_block(ei, &sm);
  for (int i = t; i < NBKT; i += 256) hist[i] = 0;
  __syncthreads();
  int e0 = b * EPB;
#pragma unroll
  for (int p = 0; p < EPB / 256; p++) {
    int e = e0 + p * 256 + t;
    if (e < N_EDGES) atomicAdd(&hist[ld_dst(ei, m, e) >> 8], 1);
  }
  __syncthreads();
  for (int i = t; i < NBKT; i += 256) ghist[b * NBKT + i] = hist[i];
}

// ---------------- pass B: per-bucket exclusive scan over blocks ----------------
__global__ __launch_bounds__(256) void scanB1_k(int* __restrict__ ghist,
                                                int* __restrict__ gtot) {
  __shared__ int ts[256];
  int t = threadIdx.x, k = blockIdx.x;
  int v = (t < NBLK_E) ? ghist[t * NBKT + k] : 0;
  ts[t] = v;
  for (int off = 1; off < 256; off <<= 1) {
    __syncthreads(); int add = (t >= off) ? ts[t - off] : 0;
    __syncthreads(); ts[t] += add;
  }
  __syncthreads();
  if (t < NBLK_E) ghist[t * NBKT + k] = ts[t] - v;
  if (t == 255) gtot[k] = ts[255];
}

// in-block exclusive scan of gtot[NBKT] -> bb[NBKT+1]
__device__ __forceinline__ void scan_gtot_block(const int* __restrict__ gtot,
                                                int* bb, int* sc) {
  int t = threadIdx.x;
  int v0 = gtot[t];
  sc[t] = v0;
  for (int off = 1; off < 256; off <<= 1) {
    __syncthreads(); int add = (t >= off) ? sc[t - off] : 0;
    __syncthreads(); sc[t] += add;
  }
  __syncthreads();
  bb[t] = sc[t] - v0;
  int base256 = sc[255];
  __syncthreads();
  int v1 = (t < NBKT - 256) ? gtot[256 + t] : 0;
  sc[t] = v1;
  for (int off = 1; off < 256; off <<= 1) {
    __syncthreads(); int add = (t >= off) ? sc[t - off] : 0;
    __syncthreads(); sc[t] += add;
  }
  __syncthreads();
  if (t < NBKT - 256) bb[256 + t] = base256 + sc[t] - v1;
  if (t == 0) bb[NBKT] = N_EDGES;
  __syncthreads();
}

// ---------------- pass C: place edges into bucket regions ----------------
__global__ __launch_bounds__(256) void scatterC_k(const int* __restrict__ ei,
                                                  const int* __restrict__ obase,
                                                  const int* __restrict__ gtot,
                                                  u32* __restrict__ colpk) {
  __shared__ int sm;
  __shared__ int cur[NBKT];
  __shared__ int bb[NBKT + 1];
  __shared__ int sc[256];
  int t = threadIdx.x, b = blockIdx.x;
  int m = detect_m_block(ei, &sm);
  scan_gtot_block(gtot, bb, sc);
  for (int i = t; i < NBKT; i += 256) cur[i] = bb[i] + obase[b * NBKT + i];
  __syncthreads();
  int e0 = b * EPB;
#pragma unroll
  for (int p = 0; p < EPB / 256; p++) {
    int e = e0 + p * 256 + t;
    if (e < N_EDGES) {
      int d = ld_dst(ei, m, e);
      int s = ld_src(ei, m, e);
      int pos = atomicAdd(&cur[d >> 8], 1);
      colpk[pos] = (u32)s | ((u32)(d & 255) << 24);
    }
  }
}

// ---------------- pass D: degrees, rowptr, dinv, exact CSR placement ----------------
__global__ __launch_bounds__(256) void fillD_k(const int* __restrict__ gtot,
                                               const u32* __restrict__ colpk,
                                               int* __restrict__ colarr,
                                               int* __restrict__ rowptr,
                                               float* __restrict__ dinv) {
  __shared__ int hist[256];
  __shared__ int cur[256];
  __shared__ int lbuf[LBUF];
  __shared__ int bb[NBKT + 1];
  __shared__ int sc[256];
  int t = threadIdx.x, b = blockIdx.x;
  scan_gtot_block(gtot, bb, sc);
  int base = bb[b], end = bb[b + 1], cnt = end - base;
  hist[t] = 0;
  __syncthreads();
  for (int i = t; i < cnt; i += 256) atomicAdd(&hist[colpk[base + i] >> 24], 1);
  __syncthreads();
  int c = hist[t];
  cur[t] = c;
  for (int off = 1; off < 256; off <<= 1) {
    __syncthreads(); int add = (t >= off) ? cur[t - off] : 0;
    __syncthreads(); cur[t] += add;
  }
  __syncthreads();
  int excl = cur[t] - c;
  int node = b * 256 + t;
  if (node < N_NODES) {
    rowptr[node] = base + excl;
    dinv[node] = rsqrtf((float)(c + 1));      // +1 self-loop
  }
  if (b == NBKT - 1 && t == 0) rowptr[N_NODES] = N_EDGES;
  __syncthreads();
  cur[t] = excl;
  __syncthreads();
  for (int i = t; i < cnt; i += 256) {
    u32 v = colpk[base + i];
    int slot = atomicAdd(&cur[v >> 24], 1);
    if (slot < LBUF) lbuf[slot] = (int)(v & 0x00FFFFFFu);
  }
  __syncthreads();
  for (int i = t; i < cnt; i += 256) colarr[base + i] = lbuf[i];
}

// ---------------- MFMA GEMM: Ysl = bf16((X @ W) * dinv[row]), sliced output -------
// 128-row tile, 512 threads / 8 waves; W in LDS once; X direct to registers
// (f32 row-major for layer 1, sliced bf16 otherwise); LDS-transposed epilogue
// emits contiguous 32B/thread per-slice stores (nt).
#define LP 136       // LDS pitch in ushorts (272B, 16B-aligned rows)
#define GROWS 128    // rows per block
#define GB1   782    // ceil(N_NODES/128)

__global__ __launch_bounds__(512, 4) void gemm_scale_k(const void* __restrict__ Xv,
                                                       int x_is_f32,
                                                       const u16* __restrict__ Wt,
                                                       const float* __restrict__ dinv,
                                                       u16* __restrict__ Y, int nrows) {
  __shared__ u16 sW[128 * LP];
  int tid = threadIdx.x;
  int r0 = blockIdx.x * GROWS;

  for (int c = tid; c < 2048; c += 512) {
    int row = c >> 4, off = (c & 15) * 8;
    *(uint4*)(&sW[row * LP + off]) = *(const uint4*)(Wt + row * DFEAT + off);
  }
  __syncthreads();

  int wave = tid >> 6, lane = tid & 63;
  int q = lane >> 4, r = lane & 15;
  int wr0 = wave * 16;
  int arow = r0 + wr0 + r;
  bool rok = (arow < nrows);

  s16x8 a[4];
  if (x_is_f32) {
    const float* Xf = (const float*)Xv + (size_t)arow * DFEAT;
#pragma unroll
    for (int kk = 0; kk < 4; kk++) {
      uint4 u = make_uint4(0, 0, 0, 0);
      if (rok) {
        int k0 = kk * 32 + q * 8;
        float4 v0 = *(const float4*)(Xf + k0);
        float4 v1 = *(const float4*)(Xf + k0 + 4);
        u.x = pack2(v0.x, v0.y); u.y = pack2(v0.z, v0.w);
        u.z = pack2(v1.x, v1.y); u.w = pack2(v1.z, v1.w);
      }
      a[kk] = *(s16x8*)&u;
    }
  } else {
    // sliced input: features kk*32+q*8 live at slice kk*2+(q>>1), half q&1
    const u16* Xb = (const u16*)Xv;
    int hh = q & 1;
#pragma unroll
    for (int kk = 0; kk < 4; kk++) {
      uint4 u = make_uint4(0, 0, 0, 0);
      if (rok) {
        int sidx = kk * 2 + (q >> 1);
        u = *(const uint4*)(Xb + (size_t)sidx * SL_STRIDE + (size_t)arow * 16 + hh * 8);
      }
      a[kk] = *(s16x8*)&u;
    }
  }

  f32x4 acc[8];
#pragma unroll
  for (int i = 0; i < 8; i++) acc[i] = (f32x4){0.f, 0.f, 0.f, 0.f};

#pragma unroll
  for (int kk = 0; kk < 4; kk++) {
    int k0 = kk * 32;
#pragma unroll
    for (int nt = 0; nt < 8; nt++) {
      s16x8 bfrag = *(const s16x8*)(&sW[(nt * 16 + r) * LP + k0 + q * 8]);
      acc[nt] = __builtin_amdgcn_mfma_f32_16x16x32_bf16(a[kk], bfrag, acc[nt], 0, 0, 0);
    }
  }

  __syncthreads();            // all sW reads done; reuse as output tile
#pragma unroll
  for (int i = 0; i < 4; i++) {
    int row = wr0 + q * 4 + i;
    int grow = r0 + row;
    float dv = (grow < nrows) ? dinv[grow] : 0.0f;
#pragma unroll
    for (int nt = 0; nt < 8; nt++) {
      sW[row * LP + nt * 16 + r] = f2bf(acc[nt][i] * dv);
    }
  }
  __syncthreads();
  // sliced store: c>>7 = slice, c&127 = row -> consecutive tid = consecutive
  // 32B entries within one slice region (fully coalesced)
  for (int c = tid; c < 1024; c += 512) {
    int sidx = c >> 7, row = c & 127;
    int grow = r0 + row;
    if (grow < nrows) {
      const u16* src = &sW[row * LP + sidx * 16];
      u16* dst = Y + (size_t)sidx * SL_STRIDE + (size_t)grow * 16;
      nt_store16(dst, *(const uint4*)src);
      nt_store16(dst + 8, *(const uint4*)(src + 8));
    }
  }
}

// ---------------- aggregation over sliced layout ----------------
// bid&7 = slice (XCD residue): each XCD gathers only from its 3.2MB slice ->
// L2-resident after warmup. 2 lanes/node (16B each), 128 nodes/block.
// colidx read via nontemporal loads (8x streamed, keep L2 for the slice).
#define AGG_CHUNKS 782                 // node chunks of 128
#define AGG_GRID   (AGG_CHUNKS * 8)    // 6256

__global__ __launch_bounds__(256) void agg_k(const u16* __restrict__ HS,
                                             const float* __restrict__ dinv,
                                             const int* __restrict__ rowptr,
                                             const int* __restrict__ colidx,
                                             const float* __restrict__ bias,
                                             u16* __restrict__ OUT, int do_relu) {
  int t = threadIdx.x, bid = blockIdx.x;
  int s = bid & 7;
  int chunk = bid >> 3;
  int node = chunk * 128 + (t >> 1);
  if (node >= N_NODES) return;
  int h = t & 1;
  const u16* base = HS + (size_t)s * SL_STRIDE + h * 8;

  int rs = rowptr[node], re = rowptr[node + 1];

  float a0, a1, a2, a3, a4, a5, a6, a7;
  {
    uint4 v = *(const uint4*)(base + (size_t)node * 16);
    a0 = bflo(v.x); a1 = bfhi(v.x); a2 = bflo(v.y); a3 = bfhi(v.y);
    a4 = bflo(v.z); a5 = bfhi(v.z); a6 = bflo(v.w); a7 = bfhi(v.w);
  }

  int j = rs;
  for (; j + 4 <= re; j += 4) {
    int i0 = __builtin_nontemporal_load(colidx + j);
    int i1 = __builtin_nontemporal_load(colidx + j + 1);
    int i2 = __builtin_nontemporal_load(colidx + j + 2);
    int i3 = __builtin_nontemporal_load(colidx + j + 3);
    uint4 w0 = *(const uint4*)(base + (size_t)i0 * 16);
    uint4 w1 = *(const uint4*)(base + (size_t)i1 * 16);
    uint4 w2 = *(const uint4*)(base + (size_t)i2 * 16);
    uint4 w3 = *(const uint4*)(base + (size_t)i3 * 16);
    a0 += bflo(w0.x) + bflo(w1.x) + bflo(w2.x) + bflo(w3.x);
    a1 += bfhi(w0.x) + bfhi(w1.x) + bfhi(w2.x) + bfhi(w3.x);
    a2 += bflo(w0.y) + bflo(w1.y) + bflo(w2.y) + bflo(w3.y);
    a3 += bfhi(w0.y) + bfhi(w1.y) + bfhi(w2.y) + bfhi(w3.y);
    a4 += bflo(w0.z) + bflo(w1.z) + bflo(w2.z) + bflo(w3.z);
    a5 += bfhi(w0.z) + bfhi(w1.z) + bfhi(w2.z) + bfhi(w3.z);
    a6 += bflo(w0.w) + bflo(w1.w) + bflo(w2.w) + bflo(w3.w);
    a7 += bfhi(w0.w) + bfhi(w1.w) + bfhi(w2.w) + bfhi(w3.w);
  }
  for (; j < re; j++) {
    int i0 = __builtin_nontemporal_load(colidx + j);
    uint4 w0 = *(const uint4*)(base + (size_t)i0 * 16);
    a0 += bflo(w0.x); a1 += bfhi(w0.x); a2 += bflo(w0.y); a3 += bfhi(w0.y);
    a4 += bflo(w0.z); a5 += bfhi(w0.z); a6 += bflo(w0.w); a7 += bfhi(w0.w);
  }

  float dv = dinv[node];
  const float* bp = bias + s * 16 + h * 8;
  float4 b0 = *(const float4*)bp;
  float4 b1 = *(const float4*)(bp + 4);
  float r0 = a0 * dv + b0.x, r1 = a1 * dv + b0.y;
  float r2 = a2 * dv + b0.z, r3 = a3 * dv + b0.w;
  float r4 = a4 * dv + b1.x, r5 = a5 * dv + b1.y;
  float r6 = a6 * dv + b1.z, r7 = a7 * dv + b1.w;
  if (do_relu) {
    r0 = fmaxf(r0, 0.f); r1 = fmaxf(r1, 0.f); r2 = fmaxf(r2, 0.f); r3 = fmaxf(r3, 0.f);
    r4 = fmaxf(r4, 0.f); r5 = fmaxf(r5, 0.f); r6 = fmaxf(r6, 0.f); r7 = fmaxf(r7, 0.f);
  }
  uint4 o;
  o.x = pack2(r0, r1); o.y = pack2(r2, r3); o.z = pack2(r4, r5); o.w = pack2(r6, r7);
  nt_store16(OUT + (size_t)s * SL_STRIDE + (size_t)node * 16 + h * 8, o);
}

// ---------------- pooling: mean over sorted batch ranges (sliced input) ----------
__global__ __launch_bounds__(256) void pool_k(const u16* __restrict__ H,
                                              const int* __restrict__ batch,
                                              const int* __restrict__ flag,
                                              float* __restrict__ OUT) {
  int g = blockIdx.x;
  int m = *flag;   // 1 if int64 batch
  int lo = lower_bound_i(batch, N_NODES, g, m);
  int hi = lower_bound_i(batch, N_NODES, g + 1, m);
  int cnt = hi - lo;
  int d2 = threadIdx.x & 63;           // u32 index within 128-feature row
  int half = threadIdx.x >> 6;
  const u16* base = H + (size_t)(d2 >> 3) * SL_STRIDE + (d2 & 7) * 2;
  float a0 = 0.f, a1 = 0.f;
  for (int row = lo + half; row < hi; row += 4) {
    u32 v = *(const u32*)(base + (size_t)row * 16);
    a0 += bflo(v); a1 += bfhi(v);
  }
  __shared__ float red0[256], red1[256];
  red0[threadIdx.x] = a0; red1[threadIdx.x] = a1;
  __syncthreads();
  if (threadIdx.x < 64) {
    float s0 = red0[d2] + red0[d2 + 64] + red0[d2 + 128] + red0[d2 + 192];
    float s1 = red1[d2] + red1[d2 + 64] + red1[d2 + 128] + red1[d2 + 192];
    float inv = 1.0f / fmaxf((float)cnt, 1.0f);
    OUT[g * DFEAT + 2 * d2]     = s0 * inv;
    OUT[g * DFEAT + 2 * d2 + 1] = s1 * inv;
  }
}

// ---------------- orchestration ----------------

extern "C" void kernel_launch(void* const* d_in, const int* in_sizes, int n_in,
                              void* d_out, int out_size, void* d_ws, size_t ws_size,
                              hipStream_t stream) {
  const float* x   = (const float*)d_in[0];
  const int* ei    = (const int*)d_in[1];
  const int* batch = (const int*)d_in[2];
  const float* W1  = (const float*)d_in[3];
  const float* b1  = (const float*)d_in[4];
  const float* W2  = (const float*)d_in[5];
  const float* b2  = (const float*)d_in[6];
  const float* W3  = (const float*)d_in[7];
  const float* b3  = (const float*)d_in[8];
  float* out = (float*)d_out;

  char* p = (char*)d_ws;
  size_t off = 0;
  auto carve = [&](size_t bytes) -> void* {
    void* q = p + off;
    off = (off + bytes + 255) & ~(size_t)255;
    return q;
  };
  int*   flag   = (int*)carve(256);
  int*   ghist  = (int*)carve((size_t)NBLK_E * NBKT * 4);   // becomes obase in-place
  int*   gtot   = (int*)carve(NBKT * 4);
  int*   rowptr = (int*)carve((N_NODES + 1) * 4);
  float* dinv   = (float*)carve(N_NODES * 4);
  u32*   colpk  = (u32*)carve((size_t)N_EDGES * 4);
  int*   colarr = (int*)carve((size_t)N_EDGES * 4);
  u16*   Wt1    = (u16*)carve(DFEAT * DFEAT * 2);
  u16*   Wt2    = (u16*)carve(DFEAT * DFEAT * 2);
  u16*   Wt3    = (u16*)carve(DFEAT * DFEAT * 2);
  u16*   bufA   = (u16*)carve(8 * SL_STRIDE * 2);           // 25.6 MB sliced
  u16*   bufB   = (u16*)carve(8 * SL_STRIDE * 2);
  (void)ws_size;

  histA_k<<<NBLK_E + 4, 256, 0, stream>>>(ei, ghist, W1, W2, W3, Wt1, Wt2, Wt3, flag);
  scanB1_k<<<NBKT, 256, 0, stream>>>(ghist, gtot);
  scatterC_k<<<NBLK_E, 256, 0, stream>>>(ei, ghist, gtot, colpk);
  fillD_k<<<NBKT, 256, 0, stream>>>(gtot, colpk, colarr, rowptr, dinv);

  gemm_scale_k<<<GB1, 512, 0, stream>>>((const void*)x, 1, Wt1, dinv, bufA, N_NODES);
  agg_k<<<AGG_GRID, 256, 0, stream>>>(bufA, dinv, rowptr, colarr, b1, bufB, 1);
  gemm_scale_k<<<GB1, 512, 0, stream>>>((const void*)bufB, 0, Wt2, dinv, bufA, N_NODES);
  agg_k<<<AGG_GRID, 256, 0, stream>>>(bufA, dinv, rowptr, colarr, b2, bufB, 1);
  gemm_scale_k<<<GB1, 512, 0, stream>>>((const void*)bufB, 0, Wt3, dinv, bufA, N_NODES);
  agg_k<<<AGG_GRID, 256, 0, stream>>>(bufA, dinv, rowptr, colarr, b3, bufB, 0);
  pool_k<<<N_GRAPHS, 256, 0, stream>>>(bufB, batch, flag, out);
}

// Round 10
// 385.647 us; speedup vs baseline: 1.5824x; 1.5824x over previous
//
#include <hip/hip_runtime.h>
#include <stdint.h>

typedef unsigned short u16;
typedef unsigned int   u32;

#define N_NODES  100000
#define N_EDGES  1600000
#define DFEAT    128
#define N_GRAPHS 512

#define NBKT   391    // buckets of 256 nodes (ceil(N/256))
#define EPB    8192   // edges per block in hist/scatter
#define NBLK_E 196    // ceil(N_EDGES/EPB)
#define LBUF   8192   // per-bucket capacity (mean 4096, sigma ~64)

typedef float f32x4 __attribute__((ext_vector_type(4)));
typedef short s16x8 __attribute__((ext_vector_type(8)));

__device__ __forceinline__ float bflo(u32 u) { return __uint_as_float(u << 16); }
__device__ __forceinline__ float bfhi(u32 u) { return __uint_as_float(u & 0xffff0000u); }
__device__ __forceinline__ u16 f2bf(float f) {
  u32 u = __float_as_uint(f);
  return (u16)((u + 0x7fffu + ((u >> 16) & 1u)) >> 16);   // RNE
}
__device__ __forceinline__ u32 pack2(float f0, float f1) {
  return (u32)f2bf(f0) | ((u32)f2bf(f1) << 16);
}

__device__ __forceinline__ int ld_src(const int* ei, int m, int e) {
  return m ? ei[2 * e] : ei[e];
}
__device__ __forceinline__ int ld_dst(const int* ei, int m, int e) {
  return m ? ei[2 * (N_EDGES + e)] : ei[N_EDGES + e];
}

// block-local int64-vs-int32 detect (odd words of first 64 edge slots all zero <=> int64)
__device__ __forceinline__ int detect_m_block(const int* __restrict__ ei, int* sm) {
  int t = threadIdx.x;
  if (t < 64) {
    int v = ei[2 * t + 1];
    unsigned long long b = __ballot(v != 0);
    if (t == 0) *sm = (b == 0ull) ? 1 : 0;
  }
  __syncthreads();
  return *sm;
}

__device__ __forceinline__ int lower_bound_i(const int* a, int n, int key, int shift) {
  int lo = 0, hi = n;
  while (lo < hi) {
    int mid = (lo + hi) >> 1;
    if (a[mid << shift] < key) lo = mid + 1; else hi = mid;
  }
  return lo;
}

#define LP 136       // LDS pitch in ushorts (272B, 16B-aligned rows)
#define GROWS 128    // rows per gemm block
#define GB1   782    // ceil(N_NODES/128)

// ---------------- FAT pass 1: gemm1 (x f32 @ W1, UNSCALED) + edge histogram -------
// gemm1 output is unscaled H1 = bf16(X@W1) (no dinv dependency), so it runs
// concurrently with the CSR-build histogram in one grid; agg1 applies the
// per-src dinv instead (r6-verified numerics).
//   blocks [0,GB1): gemm1 (W1 cvt f32->bf16-transposed inline in LDS)
//   blocks [GB1, GB1+196): per-block bucket histogram
//   +2 blocks: W2/W3 transpose-convert; +1 block: int64 flag for pool_k
__global__ __launch_bounds__(512, 4) void fat1_k(const float* __restrict__ x,
                                                 const float* __restrict__ W1,
                                                 const int* __restrict__ ei,
                                                 int* __restrict__ ghist,
                                                 const float* __restrict__ W2,
                                                 const float* __restrict__ W3,
                                                 u16* __restrict__ T2, u16* __restrict__ T3,
                                                 int* __restrict__ flag,
                                                 u16* __restrict__ Y) {
  __shared__ u16 sW[128 * LP];
  __shared__ int sm;
  __shared__ int hist[NBKT];
  int t = threadIdx.x, b = blockIdx.x;

  if (b >= GB1) {
    int hb = b - GB1;
    if (hb < NBLK_E) {               // histogram path
      int m = detect_m_block(ei, &sm);
      for (int i = t; i < NBKT; i += 512) hist[i] = 0;
      __syncthreads();
      int e0 = hb * EPB;
#pragma unroll
      for (int p = 0; p < EPB / 512; p++) {
        int e = e0 + p * 512 + t;
        if (e < N_EDGES) atomicAdd(&hist[ld_dst(ei, m, e) >> 8], 1);
      }
      __syncthreads();
      for (int i = t; i < NBKT; i += 512) ghist[hb * NBKT + i] = hist[i];
    } else if (hb < NBLK_E + 2) {    // W transpose+convert (W2, W3)
      const float* W = (hb == NBLK_E) ? W2 : W3;
      u16* T         = (hb == NBLK_E) ? T2 : T3;
      for (int i = t; i < DFEAT * DFEAT; i += 512) {
        int n = i >> 7, k = i & 127;
        T[i] = f2bf(W[k * DFEAT + n]);
      }
    } else {                          // flag for pool_k
      if (t < 64) {
        int v = ei[2 * t + 1];
        unsigned long long mm = __ballot(v != 0);
        if (t == 0) *flag = (mm == 0ull) ? 1 : 0;
      }
    }
    return;
  }

  // ---- gemm1 path: Y[r,:] = bf16(X[r,:] @ W1), X f32, unscaled ----
  int r0 = b * GROWS;
  for (int c = t; c < 4096; c += 512) {
    int k = c >> 5, n4 = (c & 31) << 2;
    float4 v = *(const float4*)(W1 + k * DFEAT + n4);
    sW[(n4 + 0) * LP + k] = f2bf(v.x);
    sW[(n4 + 1) * LP + k] = f2bf(v.y);
    sW[(n4 + 2) * LP + k] = f2bf(v.z);
    sW[(n4 + 3) * LP + k] = f2bf(v.w);
  }
  __syncthreads();

  int wave = t >> 6, lane = t & 63;
  int q = lane >> 4, r = lane & 15;
  int wr0 = wave * 16;
  int arow = r0 + wr0 + r;
  bool rok = (arow < N_NODES);

  s16x8 a[4];
  {
    const float* Xf = x + (size_t)arow * DFEAT;
#pragma unroll
    for (int kk = 0; kk < 4; kk++) {
      uint4 u = make_uint4(0, 0, 0, 0);
      if (rok) {
        int k0 = kk * 32 + q * 8;
        float4 v0 = *(const float4*)(Xf + k0);
        float4 v1 = *(const float4*)(Xf + k0 + 4);
        u.x = pack2(v0.x, v0.y); u.y = pack2(v0.z, v0.w);
        u.z = pack2(v1.x, v1.y); u.w = pack2(v1.z, v1.w);
      }
      a[kk] = *(s16x8*)&u;
    }
  }

  f32x4 acc[8];
#pragma unroll
  for (int i = 0; i < 8; i++) acc[i] = (f32x4){0.f, 0.f, 0.f, 0.f};

#pragma unroll
  for (int kk = 0; kk < 4; kk++) {
    int k0 = kk * 32;
#pragma unroll
    for (int nt = 0; nt < 8; nt++) {
      s16x8 bb = *(const s16x8*)(&sW[(nt * 16 + r) * LP + k0 + q * 8]);
      acc[nt] = __builtin_amdgcn_mfma_f32_16x16x32_bf16(a[kk], bb, acc[nt], 0, 0, 0);
    }
  }

  __syncthreads();            // W reads done; reuse sW for output tile
#pragma unroll
  for (int i = 0; i < 4; i++) {
    int row = wr0 + q * 4 + i;
#pragma unroll
    for (int nt = 0; nt < 8; nt++) {
      sW[row * LP + nt * 16 + r] = f2bf(acc[nt][i]);
    }
  }
  __syncthreads();
  for (int c = t; c < 128 * 16; c += 512) {
    int row = c >> 4, seg = c & 15;
    int grow = r0 + row;
    if (grow < N_NODES) {
      *(uint4*)(Y + (size_t)grow * DFEAT + seg * 8) = *(const uint4*)(&sW[row * LP + seg * 8]);
    }
  }
}

// ---------------- pass B: per-bucket exclusive scan over blocks ----------------
__global__ __launch_bounds__(256) void scanB1_k(int* __restrict__ ghist,
                                                int* __restrict__ gtot) {
  __shared__ int ts[256];
  int t = threadIdx.x, k = blockIdx.x;
  int v = (t < NBLK_E) ? ghist[t * NBKT + k] : 0;
  ts[t] = v;
  for (int off = 1; off < 256; off <<= 1) {
    __syncthreads(); int add = (t >= off) ? ts[t - off] : 0;
    __syncthreads(); ts[t] += add;
  }
  __syncthreads();
  if (t < NBLK_E) ghist[t * NBKT + k] = ts[t] - v;
  if (t == 255) gtot[k] = ts[255];
}

// in-block exclusive scan of gtot[NBKT] -> bb[NBKT+1]
__device__ __forceinline__ void scan_gtot_block(const int* __restrict__ gtot,
                                                int* bb, int* sc) {
  int t = threadIdx.x;
  int v0 = gtot[t];
  sc[t] = v0;
  for (int off = 1; off < 256; off <<= 1) {
    __syncthreads(); int add = (t >= off) ? sc[t - off] : 0;
    __syncthreads(); sc[t] += add;
  }
  __syncthreads();
  bb[t] = sc[t] - v0;
  int base256 = sc[255];
  __syncthreads();
  int v1 = (t < NBKT - 256) ? gtot[256 + t] : 0;
  sc[t] = v1;
  for (int off = 1; off < 256; off <<= 1) {
    __syncthreads(); int add = (t >= off) ? sc[t - off] : 0;
    __syncthreads(); sc[t] += add;
  }
  __syncthreads();
  if (t < NBKT - 256) bb[256 + t] = base256 + sc[t] - v1;
  if (t == 0) bb[NBKT] = N_EDGES;
  __syncthreads();
}

// ---------------- pass C: place edges into bucket regions ----------------
__global__ __launch_bounds__(256) void scatterC_k(const int* __restrict__ ei,
                                                  const int* __restrict__ obase,
                                                  const int* __restrict__ gtot,
                                                  u32* __restrict__ colpk) {
  __shared__ int sm;
  __shared__ int cur[NBKT];
  __shared__ int bb[NBKT + 1];
  __shared__ int sc[256];
  int t = threadIdx.x, b = blockIdx.x;
  int m = detect_m_block(ei, &sm);
  scan_gtot_block(gtot, bb, sc);
  for (int i = t; i < NBKT; i += 256) cur[i] = bb[i] + obase[b * NBKT + i];
  __syncthreads();
  int e0 = b * EPB;
#pragma unroll
  for (int p = 0; p < EPB / 256; p++) {
    int e = e0 + p * 256 + t;
    if (e < N_EDGES) {
      int d = ld_dst(ei, m, e);
      int s = ld_src(ei, m, e);
      int pos = atomicAdd(&cur[d >> 8], 1);
      colpk[pos] = (u32)s | ((u32)(d & 255) << 24);
    }
  }
}

// ---------------- pass D: degrees, rowptr, dinv, exact CSR placement ----------------
__global__ __launch_bounds__(256) void fillD_k(const int* __restrict__ gtot,
                                               const u32* __restrict__ colpk,
                                               int* __restrict__ colarr,
                                               int* __restrict__ rowptr,
                                               float* __restrict__ dinv) {
  __shared__ int hist[256];
  __shared__ int cur[256];
  __shared__ int lbuf[LBUF];
  __shared__ int bb[NBKT + 1];
  __shared__ int sc[256];
  int t = threadIdx.x, b = blockIdx.x;
  scan_gtot_block(gtot, bb, sc);
  int base = bb[b], end = bb[b + 1], cnt = end - base;
  hist[t] = 0;
  __syncthreads();
  for (int i = t; i < cnt; i += 256) atomicAdd(&hist[colpk[base + i] >> 24], 1);
  __syncthreads();
  int c = hist[t];
  cur[t] = c;
  for (int off = 1; off < 256; off <<= 1) {
    __syncthreads(); int add = (t >= off) ? cur[t - off] : 0;
    __syncthreads(); cur[t] += add;
  }
  __syncthreads();
  int excl = cur[t] - c;
  int node = b * 256 + t;
  if (node < N_NODES) {
    rowptr[node] = base + excl;
    dinv[node] = rsqrtf((float)(c + 1));      // +1 self-loop
  }
  if (b == NBKT - 1 && t == 0) rowptr[N_NODES] = N_EDGES;
  __syncthreads();
  cur[t] = excl;
  __syncthreads();
  for (int i = t; i < cnt; i += 256) {
    u32 v = colpk[base + i];
    int slot = atomicAdd(&cur[v >> 24], 1);
    if (slot < LBUF) lbuf[slot] = (int)(v & 0x00FFFFFFu);
  }
  __syncthreads();
  for (int i = t; i < cnt; i += 256) colarr[base + i] = lbuf[i];
}

// ---------------- MFMA GEMM (bf16 in): Y = bf16((X @ W) * dinv[row]) --------------
// r5-verified: 128-row tile, 512 thr / 8 waves; W in LDS once; X direct to
// registers; LDS-transposed coalesced epilogue with dinv pre-scale.
__global__ __launch_bounds__(512, 4) void gemm_scale_k(const u16* __restrict__ Xb,
                                                       const u16* __restrict__ Wt,
                                                       const float* __restrict__ dinv,
                                                       u16* __restrict__ Y, int nrows) {
  __shared__ u16 sW[128 * LP];
  int tid = threadIdx.x;
  int r0 = blockIdx.x * GROWS;

  for (int c = tid; c < 2048; c += 512) {
    int row = c >> 4, off = (c & 15) * 8;
    *(uint4*)(&sW[row * LP + off]) = *(const uint4*)(Wt + row * DFEAT + off);
  }
  __syncthreads();

  int wave = tid >> 6, lane = tid & 63;
  int q = lane >> 4, r = lane & 15;
  int wr0 = wave * 16;
  int arow = r0 + wr0 + r;
  bool rok = (arow < nrows);

  s16x8 a[4];
  {
    const u16* Xp = Xb + (size_t)arow * DFEAT;
#pragma unroll
    for (int kk = 0; kk < 4; kk++) {
      uint4 u = make_uint4(0, 0, 0, 0);
      if (rok) u = *(const uint4*)(Xp + kk * 32 + q * 8);
      a[kk] = *(s16x8*)&u;
    }
  }

  f32x4 acc[8];
#pragma unroll
  for (int i = 0; i < 8; i++) acc[i] = (f32x4){0.f, 0.f, 0.f, 0.f};

#pragma unroll
  for (int kk = 0; kk < 4; kk++) {
    int k0 = kk * 32;
#pragma unroll
    for (int nt = 0; nt < 8; nt++) {
      s16x8 bfrag = *(const s16x8*)(&sW[(nt * 16 + r) * LP + k0 + q * 8]);
      acc[nt] = __builtin_amdgcn_mfma_f32_16x16x32_bf16(a[kk], bfrag, acc[nt], 0, 0, 0);
    }
  }

  __syncthreads();
#pragma unroll
  for (int i = 0; i < 4; i++) {
    int row = wr0 + q * 4 + i;
    int grow = r0 + row;
    float dv = (grow < nrows) ? dinv[grow] : 0.0f;
#pragma unroll
    for (int nt = 0; nt < 8; nt++) {
      sW[row * LP + nt * 16 + r] = f2bf(acc[nt][i] * dv);
    }
  }
  __syncthreads();
  for (int c = tid; c < 128 * 16; c += 512) {
    int row = c >> 4, seg = c & 15;
    int grow = r0 + row;
    if (grow < nrows) {
      *(uint4*)(Y + (size_t)grow * DFEAT + seg * 8) = *(const uint4*)(&sW[row * LP + seg * 8]);
    }
  }
}

#define AGG_NB_HALF 3125               // node-blocks of 32 per half
#define AGG_GRID    6256               // 782 * 8

// ---------------- agg layer 1: unscaled H1 input, per-src dinv (r6-verified) ------
struct AccS {
  float a0, a1, a2, a3, a4, a5, a6, a7;
  __device__ __forceinline__ void add(uint4 v, float d) {
    a0 = fmaf(bflo(v.x), d, a0); a1 = fmaf(bfhi(v.x), d, a1);
    a2 = fmaf(bflo(v.y), d, a2); a3 = fmaf(bfhi(v.y), d, a3);
    a4 = fmaf(bflo(v.z), d, a4); a5 = fmaf(bfhi(v.z), d, a5);
    a6 = fmaf(bflo(v.w), d, a6); a7 = fmaf(bfhi(v.w), d, a7);
  }
};

__global__ __launch_bounds__(256) void agg_src_k(const u32* __restrict__ HS,
                                                 const float* __restrict__ dinv,
                                                 const int* __restrict__ rowptr,
                                                 const int* __restrict__ colidx,
                                                 const float* __restrict__ bias,
                                                 u32* __restrict__ OUT) {
  int t = threadIdx.x;
  int bid = blockIdx.x;
  int res = bid & 7;
  int half = res >> 2;
  int nb = (bid >> 3) * 4 + (res & 3);
  if (nb >= AGG_NB_HALF) return;

  int node = nb * 32 + (t >> 3);
  int fp = t & 7;
  int cbase = half * 32 + fp * 4;

  int s = rowptr[node], e = rowptr[node + 1];
  float dvs = dinv[node];

  AccS A;
  uint4 v = *(const uint4*)(HS + (size_t)node * 64 + cbase);   // self row
  A.a0 = bflo(v.x) * dvs; A.a1 = bfhi(v.x) * dvs;
  A.a2 = bflo(v.y) * dvs; A.a3 = bfhi(v.y) * dvs;
  A.a4 = bflo(v.z) * dvs; A.a5 = bfhi(v.z) * dvs;
  A.a6 = bflo(v.w) * dvs; A.a7 = bfhi(v.w) * dvs;

  int j = s;
  for (; j + 4 <= e; j += 4) {
    int i0 = colidx[j], i1 = colidx[j + 1], i2 = colidx[j + 2], i3 = colidx[j + 3];
    float d0 = dinv[i0], d1 = dinv[i1], d2 = dinv[i2], d3 = dinv[i3];
    uint4 w0 = *(const uint4*)(HS + (size_t)i0 * 64 + cbase);
    uint4 w1 = *(const uint4*)(HS + (size_t)i1 * 64 + cbase);
    uint4 w2 = *(const uint4*)(HS + (size_t)i2 * 64 + cbase);
    uint4 w3 = *(const uint4*)(HS + (size_t)i3 * 64 + cbase);
    A.add(w0, d0); A.add(w1, d1); A.add(w2, d2); A.add(w3, d3);
  }
  for (; j < e; j++) {
    int i0 = colidx[j];
    float d0 = dinv[i0];
    uint4 w0 = *(const uint4*)(HS + (size_t)i0 * 64 + cbase);
    A.add(w0, d0);
  }

  float4 b0 = *(const float4*)(bias + cbase * 2);
  float4 b1 = *(const float4*)(bias + cbase * 2 + 4);
  float r0 = A.a0 * dvs + b0.x, r1 = A.a1 * dvs + b0.y;
  float r2 = A.a2 * dvs + b0.z, r3 = A.a3 * dvs + b0.w;
  float r4 = A.a4 * dvs + b1.x, r5 = A.a5 * dvs + b1.y;
  float r6 = A.a6 * dvs + b1.z, r7 = A.a7 * dvs + b1.w;
  r0 = fmaxf(r0, 0.f); r1 = fmaxf(r1, 0.f); r2 = fmaxf(r2, 0.f); r3 = fmaxf(r3, 0.f);
  r4 = fmaxf(r4, 0.f); r5 = fmaxf(r5, 0.f); r6 = fmaxf(r6, 0.f); r7 = fmaxf(r7, 0.f);
  uint4 o;
  o.x = pack2(r0, r1); o.y = pack2(r2, r3); o.z = pack2(r4, r5); o.w = pack2(r6, r7);
  *(uint4*)(OUT + (size_t)node * 64 + cbase) = o;
}

// ---------------- agg layers 2,3: pre-scaled rows (r5-verified) -------------------
struct Acc8 {
  float a0, a1, a2, a3, a4, a5, a6, a7;
  __device__ __forceinline__ void add(uint4 v) {
    a0 += bflo(v.x); a1 += bfhi(v.x); a2 += bflo(v.y); a3 += bfhi(v.y);
    a4 += bflo(v.z); a5 += bfhi(v.z); a6 += bflo(v.w); a7 += bfhi(v.w);
  }
};

__global__ __launch_bounds__(256) void agg_k(const u32* __restrict__ HS,
                                             const float* __restrict__ dinv,
                                             const int* __restrict__ rowptr,
                                             const int* __restrict__ colidx,
                                             const float* __restrict__ bias,
                                             u32* __restrict__ OUT, int do_relu) {
  int t = threadIdx.x;
  int bid = blockIdx.x;
  int res = bid & 7;
  int half = res >> 2;
  int nb = (bid >> 3) * 4 + (res & 3);
  if (nb >= AGG_NB_HALF) return;

  int node = nb * 32 + (t >> 3);
  int fp = t & 7;
  int cbase = half * 32 + fp * 4;

  int s = rowptr[node], e = rowptr[node + 1];

  Acc8 A;
  uint4 v = *(const uint4*)(HS + (size_t)node * 64 + cbase);   // self row
  A.a0 = bflo(v.x); A.a1 = bfhi(v.x); A.a2 = bflo(v.y); A.a3 = bfhi(v.y);
  A.a4 = bflo(v.z); A.a5 = bfhi(v.z); A.a6 = bflo(v.w); A.a7 = bfhi(v.w);

  int j = s;
  for (; j + 4 <= e; j += 4) {
    int i0 = colidx[j], i1 = colidx[j + 1], i2 = colidx[j + 2], i3 = colidx[j + 3];
    uint4 w0 = *(const uint4*)(HS + (size_t)i0 * 64 + cbase);
    uint4 w1 = *(const uint4*)(HS + (size_t)i1 * 64 + cbase);
    uint4 w2 = *(const uint4*)(HS + (size_t)i2 * 64 + cbase);
    uint4 w3 = *(const uint4*)(HS + (size_t)i3 * 64 + cbase);
    A.add(w0); A.add(w1); A.add(w2); A.add(w3);
  }
  for (; j < e; j++) {
    int i0 = colidx[j];
    uint4 w0 = *(const uint4*)(HS + (size_t)i0 * 64 + cbase);
    A.add(w0);
  }

  float dv = dinv[node];
  float4 b0 = *(const float4*)(bias + cbase * 2);
  float4 b1 = *(const float4*)(bias + cbase * 2 + 4);
  float r0 = A.a0 * dv + b0.x, r1 = A.a1 * dv + b0.y;
  float r2 = A.a2 * dv + b0.z, r3 = A.a3 * dv + b0.w;
  float r4 = A.a4 * dv + b1.x, r5 = A.a5 * dv + b1.y;
  float r6 = A.a6 * dv + b1.z, r7 = A.a7 * dv + b1.w;
  if (do_relu) {
    r0 = fmaxf(r0, 0.f); r1 = fmaxf(r1, 0.f); r2 = fmaxf(r2, 0.f); r3 = fmaxf(r3, 0.f);
    r4 = fmaxf(r4, 0.f); r5 = fmaxf(r5, 0.f); r6 = fmaxf(r6, 0.f); r7 = fmaxf(r7, 0.f);
  }
  uint4 o;
  o.x = pack2(r0, r1); o.y = pack2(r2, r3); o.z = pack2(r4, r5); o.w = pack2(r6, r7);
  *(uint4*)(OUT + (size_t)node * 64 + cbase) = o;
}

// ---------------- pooling: mean over sorted batch ranges ----------------
__global__ __launch_bounds__(256) void pool_k(const u32* __restrict__ H,
                                              const int* __restrict__ batch,
                                              const int* __restrict__ flag,
                                              float* __restrict__ OUT) {
  int g = blockIdx.x;
  int m = *flag;   // 1 if int64 batch
  int lo = lower_bound_i(batch, N_NODES, g, m);
  int hi = lower_bound_i(batch, N_NODES, g + 1, m);
  int cnt = hi - lo;
  int d2 = threadIdx.x & 63;
  int half = threadIdx.x >> 6;
  float a0 = 0.f, a1 = 0.f;
  for (int row = lo + half; row < hi; row += 4) {
    u32 v = H[(size_t)row * 64 + d2];
    a0 += bflo(v); a1 += bfhi(v);
  }
  __shared__ float red0[256], red1[256];
  red0[threadIdx.x] = a0; red1[threadIdx.x] = a1;
  __syncthreads();
  if (threadIdx.x < 64) {
    float s0 = red0[d2] + red0[d2 + 64] + red0[d2 + 128] + red0[d2 + 192];
    float s1 = red1[d2] + red1[d2 + 64] + red1[d2 + 128] + red1[d2 + 192];
    float inv = 1.0f / fmaxf((float)cnt, 1.0f);
    OUT[g * DFEAT + 2 * d2]     = s0 * inv;
    OUT[g * DFEAT + 2 * d2 + 1] = s1 * inv;
  }
}

// ---------------- orchestration ----------------

extern "C" void kernel_launch(void* const* d_in, const int* in_sizes, int n_in,
                              void* d_out, int out_size, void* d_ws, size_t ws_size,
                              hipStream_t stream) {
  const float* x   = (const float*)d_in[0];
  const int* ei    = (const int*)d_in[1];
  const int* batch = (const int*)d_in[2];
  const float* W1  = (const float*)d_in[3];
  const float* b1  = (const float*)d_in[4];
  const float* W2  = (const float*)d_in[5];
  const float* b2  = (const float*)d_in[6];
  const float* W3  = (const float*)d_in[7];
  const float* b3  = (const float*)d_in[8];
  float* out = (float*)d_out;

  char* p = (char*)d_ws;
  size_t off = 0;
  auto carve = [&](size_t bytes) -> void* {
    void* q = p + off;
    off = (off + bytes + 255) & ~(size_t)255;
    return q;
  };
  int*   flag   = (int*)carve(256);
  int*   ghist  = (int*)carve((size_t)NBLK_E * NBKT * 4);   // becomes obase in-place
  int*   gtot   = (int*)carve(NBKT * 4);
  int*   rowptr = (int*)carve((N_NODES + 1) * 4);
  float* dinv   = (float*)carve(N_NODES * 4);
  u32*   colpk  = (u32*)carve((size_t)N_EDGES * 4);
  int*   colarr = (int*)carve((size_t)N_EDGES * 4);
  u16*   Wt2    = (u16*)carve(DFEAT * DFEAT * 2);
  u16*   Wt3    = (u16*)carve(DFEAT * DFEAT * 2);
  u32*   bufA   = (u32*)carve((size_t)N_NODES * 64 * 4);
  u32*   bufB   = (u32*)carve((size_t)N_NODES * 64 * 4);
  (void)ws_size;

  const int FAT_GRID = GB1 + NBLK_E + 3;   // 981

  fat1_k<<<FAT_GRID, 512, 0, stream>>>(x, W1, ei, ghist, W2, W3, Wt2, Wt3, flag,
                                       (u16*)bufA);
  scanB1_k<<<NBKT, 256, 0, stream>>>(ghist, gtot);
  scatterC_k<<<NBLK_E, 256, 0, stream>>>(ei, ghist, gtot, colpk);
  fillD_k<<<NBKT, 256, 0, stream>>>(gtot, colpk, colarr, rowptr, dinv);

  agg_src_k<<<AGG_GRID, 256, 0, stream>>>(bufA, dinv, rowptr, colarr, b1, bufB);
  gemm_scale_k<<<GB1, 512, 0, stream>>>((const u16*)bufB, Wt2, dinv, (u16*)bufA, N_NODES);
  agg_k<<<AGG_GRID, 256, 0, stream>>>(bufA, dinv, rowptr, colarr, b2, bufB, 1);
  gemm_scale_k<<<GB1, 512, 0, stream>>>((const u16*)bufB, Wt3, dinv, (u16*)bufA, N_NODES);
  agg_k<<<AGG_GRID, 256, 0, stream>>>(bufA, dinv, rowptr, colarr, b3, bufB, 0);
  pool_k<<<N_GRAPHS, 256, 0, stream>>>(bufB, batch, flag, out);
}

// Round 11
// 383.451 us; speedup vs baseline: 1.5914x; 1.0057x over previous
//
#include <hip/hip_runtime.h>
#include <stdint.h>

typedef unsigned short u16;
typedef unsigned int   u32;

#define N_NODES  100000
#define N_EDGES  1600000
#define DFEAT    128
#define N_GRAPHS 512

#define NBKT   391    // buckets of 256 nodes (ceil(N/256))
#define EPB    8192   // edges per block in hist/scatter
#define NBLK_E 196    // ceil(N_EDGES/EPB)
#define LBUF   8192   // per-bucket capacity (mean 4096, sigma ~64)

typedef float f32x4 __attribute__((ext_vector_type(4)));
typedef short s16x8 __attribute__((ext_vector_type(8)));

__device__ __forceinline__ float bflo(u32 u) { return __uint_as_float(u << 16); }
__device__ __forceinline__ float bfhi(u32 u) { return __uint_as_float(u & 0xffff0000u); }
__device__ __forceinline__ u16 f2bf(float f) {
  u32 u = __float_as_uint(f);
  return (u16)((u + 0x7fffu + ((u >> 16) & 1u)) >> 16);   // RNE
}
__device__ __forceinline__ u32 pack2(float f0, float f1) {
  return (u32)f2bf(f0) | ((u32)f2bf(f1) << 16);
}

__device__ __forceinline__ int ld_src(const int* ei, int m, int e) {
  return m ? ei[2 * e] : ei[e];
}
__device__ __forceinline__ int ld_dst(const int* ei, int m, int e) {
  return m ? ei[2 * (N_EDGES + e)] : ei[N_EDGES + e];
}

// block-local int64-vs-int32 detect (odd words of first 64 edge slots all zero <=> int64)
__device__ __forceinline__ int detect_m_block(const int* __restrict__ ei, int* sm) {
  int t = threadIdx.x;
  if (t < 64) {
    int v = ei[2 * t + 1];
    unsigned long long b = __ballot(v != 0);
    if (t == 0) *sm = (b == 0ull) ? 1 : 0;
  }
  __syncthreads();
  return *sm;
}

__device__ __forceinline__ int lower_bound_i(const int* a, int n, int key, int shift) {
  int lo = 0, hi = n;
  while (lo < hi) {
    int mid = (lo + hi) >> 1;
    if (a[mid << shift] < key) lo = mid + 1; else hi = mid;
  }
  return lo;
}

#define LP 136       // LDS pitch in ushorts (272B, 16B-aligned rows)
#define GROWS 128    // rows per gemm1 block (fat1)
#define GB1   782    // ceil(N_NODES/128)
#define G2ROWS 64    // rows per bf16-gemm block (r11 probe: halve block latency,
                     // 4 blocks/CU co-resident, grid 1563)
#define GB2   1563   // ceil(N_NODES/64)

// ---------------- FAT pass 1: gemm1 (x f32 @ W1, UNSCALED) + edge histogram -------
// gemm1 output is unscaled H1 = bf16(X@W1) (no dinv dependency), so it runs
// concurrently with the CSR-build histogram in one grid; agg1 applies the
// per-src dinv instead (r6-verified numerics).
//   blocks [0,GB1): gemm1 (W1 cvt f32->bf16-transposed inline in LDS)
//   blocks [GB1, GB1+196): per-block bucket histogram
//   +2 blocks: W2/W3 transpose-convert; +1 block: int64 flag for pool_k
__global__ __launch_bounds__(512, 4) void fat1_k(const float* __restrict__ x,
                                                 const float* __restrict__ W1,
                                                 const int* __restrict__ ei,
                                                 int* __restrict__ ghist,
                                                 const float* __restrict__ W2,
                                                 const float* __restrict__ W3,
                                                 u16* __restrict__ T2, u16* __restrict__ T3,
                                                 int* __restrict__ flag,
                                                 u16* __restrict__ Y) {
  __shared__ u16 sW[128 * LP];
  __shared__ int sm;
  __shared__ int hist[NBKT];
  int t = threadIdx.x, b = blockIdx.x;

  if (b >= GB1) {
    int hb = b - GB1;
    if (hb < NBLK_E) {               // histogram path
      int m = detect_m_block(ei, &sm);
      for (int i = t; i < NBKT; i += 512) hist[i] = 0;
      __syncthreads();
      int e0 = hb * EPB;
#pragma unroll
      for (int p = 0; p < EPB / 512; p++) {
        int e = e0 + p * 512 + t;
        if (e < N_EDGES) atomicAdd(&hist[ld_dst(ei, m, e) >> 8], 1);
      }
      __syncthreads();
      for (int i = t; i < NBKT; i += 512) ghist[hb * NBKT + i] = hist[i];
    } else if (hb < NBLK_E + 2) {    // W transpose+convert (W2, W3)
      const float* W = (hb == NBLK_E) ? W2 : W3;
      u16* T         = (hb == NBLK_E) ? T2 : T3;
      for (int i = t; i < DFEAT * DFEAT; i += 512) {
        int n = i >> 7, k = i & 127;
        T[i] = f2bf(W[k * DFEAT + n]);
      }
    } else {                          // flag for pool_k
      if (t < 64) {
        int v = ei[2 * t + 1];
        unsigned long long mm = __ballot(v != 0);
        if (t == 0) *flag = (mm == 0ull) ? 1 : 0;
      }
    }
    return;
  }

  // ---- gemm1 path: Y[r,:] = bf16(X[r,:] @ W1), X f32, unscaled ----
  int r0 = b * GROWS;
  for (int c = t; c < 4096; c += 512) {
    int k = c >> 5, n4 = (c & 31) << 2;
    float4 v = *(const float4*)(W1 + k * DFEAT + n4);
    sW[(n4 + 0) * LP + k] = f2bf(v.x);
    sW[(n4 + 1) * LP + k] = f2bf(v.y);
    sW[(n4 + 2) * LP + k] = f2bf(v.z);
    sW[(n4 + 3) * LP + k] = f2bf(v.w);
  }
  __syncthreads();

  int wave = t >> 6, lane = t & 63;
  int q = lane >> 4, r = lane & 15;
  int wr0 = wave * 16;
  int arow = r0 + wr0 + r;
  bool rok = (arow < N_NODES);

  s16x8 a[4];
  {
    const float* Xf = x + (size_t)arow * DFEAT;
#pragma unroll
    for (int kk = 0; kk < 4; kk++) {
      uint4 u = make_uint4(0, 0, 0, 0);
      if (rok) {
        int k0 = kk * 32 + q * 8;
        float4 v0 = *(const float4*)(Xf + k0);
        float4 v1 = *(const float4*)(Xf + k0 + 4);
        u.x = pack2(v0.x, v0.y); u.y = pack2(v0.z, v0.w);
        u.z = pack2(v1.x, v1.y); u.w = pack2(v1.z, v1.w);
      }
      a[kk] = *(s16x8*)&u;
    }
  }

  f32x4 acc[8];
#pragma unroll
  for (int i = 0; i < 8; i++) acc[i] = (f32x4){0.f, 0.f, 0.f, 0.f};

#pragma unroll
  for (int kk = 0; kk < 4; kk++) {
    int k0 = kk * 32;
#pragma unroll
    for (int nt = 0; nt < 8; nt++) {
      s16x8 bb = *(const s16x8*)(&sW[(nt * 16 + r) * LP + k0 + q * 8]);
      acc[nt] = __builtin_amdgcn_mfma_f32_16x16x32_bf16(a[kk], bb, acc[nt], 0, 0, 0);
    }
  }

  __syncthreads();            // W reads done; reuse sW for output tile
#pragma unroll
  for (int i = 0; i < 4; i++) {
    int row = wr0 + q * 4 + i;
#pragma unroll
    for (int nt = 0; nt < 8; nt++) {
      sW[row * LP + nt * 16 + r] = f2bf(acc[nt][i]);
    }
  }
  __syncthreads();
  for (int c = t; c < 128 * 16; c += 512) {
    int row = c >> 4, seg = c & 15;
    int grow = r0 + row;
    if (grow < N_NODES) {
      *(uint4*)(Y + (size_t)grow * DFEAT + seg * 8) = *(const uint4*)(&sW[row * LP + seg * 8]);
    }
  }
}

// ---------------- pass B: per-bucket exclusive scan over blocks ----------------
__global__ __launch_bounds__(256) void scanB1_k(int* __restrict__ ghist,
                                                int* __restrict__ gtot) {
  __shared__ int ts[256];
  int t = threadIdx.x, k = blockIdx.x;
  int v = (t < NBLK_E) ? ghist[t * NBKT + k] : 0;
  ts[t] = v;
  for (int off = 1; off < 256; off <<= 1) {
    __syncthreads(); int add = (t >= off) ? ts[t - off] : 0;
    __syncthreads(); ts[t] += add;
  }
  __syncthreads();
  if (t < NBLK_E) ghist[t * NBKT + k] = ts[t] - v;
  if (t == 255) gtot[k] = ts[255];
}

// in-block exclusive scan of gtot[NBKT] -> bb[NBKT+1]
__device__ __forceinline__ void scan_gtot_block(const int* __restrict__ gtot,
                                                int* bb, int* sc) {
  int t = threadIdx.x;
  int v0 = gtot[t];
  sc[t] = v0;
  for (int off = 1; off < 256; off <<= 1) {
    __syncthreads(); int add = (t >= off) ? sc[t - off] : 0;
    __syncthreads(); sc[t] += add;
  }
  __syncthreads();
  bb[t] = sc[t] - v0;
  int base256 = sc[255];
  __syncthreads();
  int v1 = (t < NBKT - 256) ? gtot[256 + t] : 0;
  sc[t] = v1;
  for (int off = 1; off < 256; off <<= 1) {
    __syncthreads(); int add = (t >= off) ? sc[t - off] : 0;
    __syncthreads(); sc[t] += add;
  }
  __syncthreads();
  if (t < NBKT - 256) bb[256 + t] = base256 + sc[t] - v1;
  if (t == 0) bb[NBKT] = N_EDGES;
  __syncthreads();
}

// ---------------- pass C: place edges into bucket regions ----------------
__global__ __launch_bounds__(256) void scatterC_k(const int* __restrict__ ei,
                                                  const int* __restrict__ obase,
                                                  const int* __restrict__ gtot,
                                                  u32* __restrict__ colpk) {
  __shared__ int sm;
  __shared__ int cur[NBKT];
  __shared__ int bb[NBKT + 1];
  __shared__ int sc[256];
  int t = threadIdx.x, b = blockIdx.x;
  int m = detect_m_block(ei, &sm);
  scan_gtot_block(gtot, bb, sc);
  for (int i = t; i < NBKT; i += 256) cur[i] = bb[i] + obase[b * NBKT + i];
  __syncthreads();
  int e0 = b * EPB;
#pragma unroll
  for (int p = 0; p < EPB / 256; p++) {
    int e = e0 + p * 256 + t;
    if (e < N_EDGES) {
      int d = ld_dst(ei, m, e);
      int s = ld_src(ei, m, e);
      int pos = atomicAdd(&cur[d >> 8], 1);
      colpk[pos] = (u32)s | ((u32)(d & 255) << 24);
    }
  }
}

// ---------------- pass D: degrees, rowptr, dinv, exact CSR placement ----------------
__global__ __launch_bounds__(256) void fillD_k(const int* __restrict__ gtot,
                                               const u32* __restrict__ colpk,
                                               int* __restrict__ colarr,
                                               int* __restrict__ rowptr,
                                               float* __restrict__ dinv) {
  __shared__ int hist[256];
  __shared__ int cur[256];
  __shared__ int lbuf[LBUF];
  __shared__ int bb[NBKT + 1];
  __shared__ int sc[256];
  int t = threadIdx.x, b = blockIdx.x;
  scan_gtot_block(gtot, bb, sc);
  int base = bb[b], end = bb[b + 1], cnt = end - base;
  hist[t] = 0;
  __syncthreads();
  for (int i = t; i < cnt; i += 256) atomicAdd(&hist[colpk[base + i] >> 24], 1);
  __syncthreads();
  int c = hist[t];
  cur[t] = c;
  for (int off = 1; off < 256; off <<= 1) {
    __syncthreads(); int add = (t >= off) ? cur[t - off] : 0;
    __syncthreads(); cur[t] += add;
  }
  __syncthreads();
  int excl = cur[t] - c;
  int node = b * 256 + t;
  if (node < N_NODES) {
    rowptr[node] = base + excl;
    dinv[node] = rsqrtf((float)(c + 1));      // +1 self-loop
  }
  if (b == NBKT - 1 && t == 0) rowptr[N_NODES] = N_EDGES;
  __syncthreads();
  cur[t] = excl;
  __syncthreads();
  for (int i = t; i < cnt; i += 256) {
    u32 v = colpk[base + i];
    int slot = atomicAdd(&cur[v >> 24], 1);
    if (slot < LBUF) lbuf[slot] = (int)(v & 0x00FFFFFFu);
  }
  __syncthreads();
  for (int i = t; i < cnt; i += 256) colarr[base + i] = lbuf[i];
}

// ---------------- MFMA GEMM (bf16 in): Y = bf16((X @ W) * dinv[row]) --------------
// r11 probe: 64-row tile, 256 threads / 4 waves (one 16-row strip per wave).
// W still staged in LDS (r3's 64-row failure was W-from-global, NOT tile size).
// LDS 34.8KB -> 4 blocks/CU co-resident, grid 1563: per-block latency halves
// and block rounds pipeline 4-deep instead of ~1.
__global__ __launch_bounds__(256, 4) void gemm_scale_k(const u16* __restrict__ Xb,
                                                       const u16* __restrict__ Wt,
                                                       const float* __restrict__ dinv,
                                                       u16* __restrict__ Y, int nrows) {
  __shared__ u16 sW[128 * LP];
  int tid = threadIdx.x;
  int r0 = blockIdx.x * G2ROWS;

  for (int c = tid; c < 2048; c += 256) {
    int row = c >> 4, off = (c & 15) * 8;
    *(uint4*)(&sW[row * LP + off]) = *(const uint4*)(Wt + row * DFEAT + off);
  }
  __syncthreads();

  int wave = tid >> 6, lane = tid & 63;
  int q = lane >> 4, r = lane & 15;
  int wr0 = wave * 16;
  int arow = r0 + wr0 + r;
  bool rok = (arow < nrows);

  s16x8 a[4];
  {
    const u16* Xp = Xb + (size_t)arow * DFEAT;
#pragma unroll
    for (int kk = 0; kk < 4; kk++) {
      uint4 u = make_uint4(0, 0, 0, 0);
      if (rok) u = *(const uint4*)(Xp + kk * 32 + q * 8);
      a[kk] = *(s16x8*)&u;
    }
  }

  f32x4 acc[8];
#pragma unroll
  for (int i = 0; i < 8; i++) acc[i] = (f32x4){0.f, 0.f, 0.f, 0.f};

#pragma unroll
  for (int kk = 0; kk < 4; kk++) {
    int k0 = kk * 32;
#pragma unroll
    for (int nt = 0; nt < 8; nt++) {
      s16x8 bfrag = *(const s16x8*)(&sW[(nt * 16 + r) * LP + k0 + q * 8]);
      acc[nt] = __builtin_amdgcn_mfma_f32_16x16x32_bf16(a[kk], bfrag, acc[nt], 0, 0, 0);
    }
  }

  __syncthreads();            // all W reads done; reuse rows [0,64) as output tile
#pragma unroll
  for (int i = 0; i < 4; i++) {
    int row = wr0 + q * 4 + i;           // 0..63
    int grow = r0 + row;
    float dv = (grow < nrows) ? dinv[grow] : 0.0f;
#pragma unroll
    for (int nt = 0; nt < 8; nt++) {
      sW[row * LP + nt * 16 + r] = f2bf(acc[nt][i] * dv);
    }
  }
  __syncthreads();
  for (int c = tid; c < G2ROWS * 16; c += 256) {
    int row = c >> 4, seg = c & 15;
    int grow = r0 + row;
    if (grow < nrows) {
      *(uint4*)(Y + (size_t)grow * DFEAT + seg * 8) = *(const uint4*)(&sW[row * LP + seg * 8]);
    }
  }
}

#define AGG_NB_HALF 3125               // node-blocks of 32 per half
#define AGG_GRID    6256               // 782 * 8

// ---------------- agg layer 1: unscaled H1 input, per-src dinv (r6-verified) ------
struct AccS {
  float a0, a1, a2, a3, a4, a5, a6, a7;
  __device__ __forceinline__ void add(uint4 v, float d) {
    a0 = fmaf(bflo(v.x), d, a0); a1 = fmaf(bfhi(v.x), d, a1);
    a2 = fmaf(bflo(v.y), d, a2); a3 = fmaf(bfhi(v.y), d, a3);
    a4 = fmaf(bflo(v.z), d, a4); a5 = fmaf(bfhi(v.z), d, a5);
    a6 = fmaf(bflo(v.w), d, a6); a7 = fmaf(bfhi(v.w), d, a7);
  }
};

__global__ __launch_bounds__(256) void agg_src_k(const u32* __restrict__ HS,
                                                 const float* __restrict__ dinv,
                                                 const int* __restrict__ rowptr,
                                                 const int* __restrict__ colidx,
                                                 const float* __restrict__ bias,
                                                 u32* __restrict__ OUT) {
  int t = threadIdx.x;
  int bid = blockIdx.x;
  int res = bid & 7;
  int half = res >> 2;
  int nb = (bid >> 3) * 4 + (res & 3);
  if (nb >= AGG_NB_HALF) return;

  int node = nb * 32 + (t >> 3);
  int fp = t & 7;
  int cbase = half * 32 + fp * 4;

  int s = rowptr[node], e = rowptr[node + 1];
  float dvs = dinv[node];

  AccS A;
  uint4 v = *(const uint4*)(HS + (size_t)node * 64 + cbase);   // self row
  A.a0 = bflo(v.x) * dvs; A.a1 = bfhi(v.x) * dvs;
  A.a2 = bflo(v.y) * dvs; A.a3 = bfhi(v.y) * dvs;
  A.a4 = bflo(v.z) * dvs; A.a5 = bfhi(v.z) * dvs;
  A.a6 = bflo(v.w) * dvs; A.a7 = bfhi(v.w) * dvs;

  int j = s;
  for (; j + 4 <= e; j += 4) {
    int i0 = colidx[j], i1 = colidx[j + 1], i2 = colidx[j + 2], i3 = colidx[j + 3];
    float d0 = dinv[i0], d1 = dinv[i1], d2 = dinv[i2], d3 = dinv[i3];
    uint4 w0 = *(const uint4*)(HS + (size_t)i0 * 64 + cbase);
    uint4 w1 = *(const uint4*)(HS + (size_t)i1 * 64 + cbase);
    uint4 w2 = *(const uint4*)(HS + (size_t)i2 * 64 + cbase);
    uint4 w3 = *(const uint4*)(HS + (size_t)i3 * 64 + cbase);
    A.add(w0, d0); A.add(w1, d1); A.add(w2, d2); A.add(w3, d3);
  }
  for (; j < e; j++) {
    int i0 = colidx[j];
    float d0 = dinv[i0];
    uint4 w0 = *(const uint4*)(HS + (size_t)i0 * 64 + cbase);
    A.add(w0, d0);
  }

  float4 b0 = *(const float4*)(bias + cbase * 2);
  float4 b1 = *(const float4*)(bias + cbase * 2 + 4);
  float r0 = A.a0 * dvs + b0.x, r1 = A.a1 * dvs + b0.y;
  float r2 = A.a2 * dvs + b0.z, r3 = A.a3 * dvs + b0.w;
  float r4 = A.a4 * dvs + b1.x, r5 = A.a5 * dvs + b1.y;
  float r6 = A.a6 * dvs + b1.z, r7 = A.a7 * dvs + b1.w;
  r0 = fmaxf(r0, 0.f); r1 = fmaxf(r1, 0.f); r2 = fmaxf(r2, 0.f); r3 = fmaxf(r3, 0.f);
  r4 = fmaxf(r4, 0.f); r5 = fmaxf(r5, 0.f); r6 = fmaxf(r6, 0.f); r7 = fmaxf(r7, 0.f);
  uint4 o;
  o.x = pack2(r0, r1); o.y = pack2(r2, r3); o.z = pack2(r4, r5); o.w = pack2(r6, r7);
  *(uint4*)(OUT + (size_t)node * 64 + cbase) = o;
}

// ---------------- agg layers 2,3: pre-scaled rows (r5-verified) -------------------
struct Acc8 {
  float a0, a1, a2, a3, a4, a5, a6, a7;
  __device__ __forceinline__ void add(uint4 v) {
    a0 += bflo(v.x); a1 += bfhi(v.x); a2 += bflo(v.y); a3 += bfhi(v.y);
    a4 += bflo(v.z); a5 += bfhi(v.z); a6 += bflo(v.w); a7 += bfhi(v.w);
  }
};

__global__ __launch_bounds__(256) void agg_k(const u32* __restrict__ HS,
                                             const float* __restrict__ dinv,
                                             const int* __restrict__ rowptr,
                                             const int* __restrict__ colidx,
                                             const float* __restrict__ bias,
                                             u32* __restrict__ OUT, int do_relu) {
  int t = threadIdx.x;
  int bid = blockIdx.x;
  int res = bid & 7;
  int half = res >> 2;
  int nb = (bid >> 3) * 4 + (res & 3);
  if (nb >= AGG_NB_HALF) return;

  int node = nb * 32 + (t >> 3);
  int fp = t & 7;
  int cbase = half * 32 + fp * 4;

  int s = rowptr[node], e = rowptr[node + 1];

  Acc8 A;
  uint4 v = *(const uint4*)(HS + (size_t)node * 64 + cbase);   // self row
  A.a0 = bflo(v.x); A.a1 = bfhi(v.x); A.a2 = bflo(v.y); A.a3 = bfhi(v.y);
  A.a4 = bflo(v.z); A.a5 = bfhi(v.z); A.a6 = bflo(v.w); A.a7 = bfhi(v.w);

  int j = s;
  for (; j + 4 <= e; j += 4) {
    int i0 = colidx[j], i1 = colidx[j + 1], i2 = colidx[j + 2], i3 = colidx[j + 3];
    uint4 w0 = *(const uint4*)(HS + (size_t)i0 * 64 + cbase);
    uint4 w1 = *(const uint4*)(HS + (size_t)i1 * 64 + cbase);
    uint4 w2 = *(const uint4*)(HS + (size_t)i2 * 64 + cbase);
    uint4 w3 = *(const uint4*)(HS + (size_t)i3 * 64 + cbase);
    A.add(w0); A.add(w1); A.add(w2); A.add(w3);
  }
  for (; j < e; j++) {
    int i0 = colidx[j];
    uint4 w0 = *(const uint4*)(HS + (size_t)i0 * 64 + cbase);
    A.add(w0);
  }

  float dv = dinv[node];
  float4 b0 = *(const float4*)(bias + cbase * 2);
  float4 b1 = *(const float4*)(bias + cbase * 2 + 4);
  float r0 = A.a0 * dv + b0.x, r1 = A.a1 * dv + b0.y;
  float r2 = A.a2 * dv + b0.z, r3 = A.a3 * dv + b0.w;
  float r4 = A.a4 * dv + b1.x, r5 = A.a5 * dv + b1.y;
  float r6 = A.a6 * dv + b1.z, r7 = A.a7 * dv + b1.w;
  if (do_relu) {
    r0 = fmaxf(r0, 0.f); r1 = fmaxf(r1, 0.f); r2 = fmaxf(r2, 0.f); r3 = fmaxf(r3, 0.f);
    r4 = fmaxf(r4, 0.f); r5 = fmaxf(r5, 0.f); r6 = fmaxf(r6, 0.f); r7 = fmaxf(r7, 0.f);
  }
  uint4 o;
  o.x = pack2(r0, r1); o.y = pack2(r2, r3); o.z = pack2(r4, r5); o.w = pack2(r6, r7);
  *(uint4*)(OUT + (size_t)node * 64 + cbase) = o;
}

// ---------------- pooling: mean over sorted batch ranges ----------------
__global__ __launch_bounds__(256) void pool_k(const u32* __restrict__ H,
                                              const int* __restrict__ batch,
                                              const int* __restrict__ flag,
                                              float* __restrict__ OUT) {
  int g = blockIdx.x;
  int m = *flag;   // 1 if int64 batch
  int lo = lower_bound_i(batch, N_NODES, g, m);
  int hi = lower_bound_i(batch, N_NODES, g + 1, m);
  int cnt = hi - lo;
  int d2 = threadIdx.x & 63;
  int half = threadIdx.x >> 6;
  float a0 = 0.f, a1 = 0.f;
  for (int row = lo + half; row < hi; row += 4) {
    u32 v = H[(size_t)row * 64 + d2];
    a0 += bflo(v); a1 += bfhi(v);
  }
  __shared__ float red0[256], red1[256];
  red0[threadIdx.x] = a0; red1[threadIdx.x] = a1;
  __syncthreads();
  if (threadIdx.x < 64) {
    float s0 = red0[d2] + red0[d2 + 64] + red0[d2 + 128] + red0[d2 + 192];
    float s1 = red1[d2] + red1[d2 + 64] + red1[d2 + 128] + red1[d2 + 192];
    float inv = 1.0f / fmaxf((float)cnt, 1.0f);
    OUT[g * DFEAT + 2 * d2]     = s0 * inv;
    OUT[g * DFEAT + 2 * d2 + 1] = s1 * inv;
  }
}

// ---------------- orchestration ----------------

extern "C" void kernel_launch(void* const* d_in, const int* in_sizes, int n_in,
                              void* d_out, int out_size, void* d_ws, size_t ws_size,
                              hipStream_t stream) {
  const float* x   = (const float*)d_in[0];
  const int* ei    = (const int*)d_in[1];
  const int* batch = (const int*)d_in[2];
  const float* W1  = (const float*)d_in[3];
  const float* b1  = (const float*)d_in[4];
  const float* W2  = (const float*)d_in[5];
  const float* b2  = (const float*)d_in[6];
  const float* W3  = (const float*)d_in[7];
  const float* b3  = (const float*)d_in[8];
  float* out = (float*)d_out;

  char* p = (char*)d_ws;
  size_t off = 0;
  auto carve = [&](size_t bytes) -> void* {
    void* q = p + off;
    off = (off + bytes + 255) & ~(size_t)255;
    return q;
  };
  int*   flag   = (int*)carve(256);
  int*   ghist  = (int*)carve((size_t)NBLK_E * NBKT * 4);   // becomes obase in-place
  int*   gtot   = (int*)carve(NBKT * 4);
  int*   rowptr = (int*)carve((N_NODES + 1) * 4);
  float* dinv   = (float*)carve(N_NODES * 4);
  u32*   colpk  = (u32*)carve((size_t)N_EDGES * 4);
  int*   colarr = (int*)carve((size_t)N_EDGES * 4);
  u16*   Wt2    = (u16*)carve(DFEAT * DFEAT * 2);
  u16*   Wt3    = (u16*)carve(DFEAT * DFEAT * 2);
  u32*   bufA   = (u32*)carve((size_t)N_NODES * 64 * 4);
  u32*   bufB   = (u32*)carve((size_t)N_NODES * 64 * 4);
  (void)ws_size;

  const int FAT_GRID = GB1 + NBLK_E + 3;   // 981

  fat1_k<<<FAT_GRID, 512, 0, stream>>>(x, W1, ei, ghist, W2, W3, Wt2, Wt3, flag,
                                       (u16*)bufA);
  scanB1_k<<<NBKT, 256, 0, stream>>>(ghist, gtot);
  scatterC_k<<<NBLK_E, 256, 0, stream>>>(ei, ghist, gtot, colpk);
  fillD_k<<<NBKT, 256, 0, stream>>>(gtot, colpk, colarr, rowptr, dinv);

  agg_src_k<<<AGG_GRID, 256, 0, stream>>>(bufA, dinv, rowptr, colarr, b1, bufB);
  gemm_scale_k<<<GB2, 256, 0, stream>>>((const u16*)bufB, Wt2, dinv, (u16*)bufA, N_NODES);
  agg_k<<<AGG_GRID, 256, 0, stream>>>(bufA, dinv, rowptr, colarr, b2, bufB, 1);
  gemm_scale_k<<<GB2, 256, 0, stream>>>((const u16*)bufB, Wt3, dinv, (u16*)bufA, N_NODES);
  agg_k<<<AGG_GRID, 256, 0, stream>>>(bufA, dinv, rowptr, colarr, b3, bufB, 0);
  pool_k<<<N_GRAPHS, 256, 0, stream>>>(bufB, batch, flag, out);
}